// Round 10
// baseline (423.476 us; speedup 1.0000x reference)
//
#include <hip/hip_runtime.h>
#include <hip/hip_bf16.h>

// HeteroAttLayer: h = tanh(hs @ W^T + b); att = softmax(mean_n h.meta); out = sum_c att[c]*h[c]
// C=4, N=300000, D=128.
// R10 = R9 + score occupancy 4->6 blocks/CU (LDS 24.5KB allows it; VGPR=60, no pressure)
//       and explicit issue-all-loads-then-pack staging (full vmcnt depth before first wait).

#define C_CH 4
#define N_NODES 300000
#define D_DIM 128
#define M_TILE 96
#define N_TILES (N_NODES / M_TILE)          // 3125 exactly, no tail
#define TILE_BYTES (M_TILE * D_DIM)         // 12288 int8 per (tile, channel)
#define H_TILE_BYTES (C_CH * TILE_BYTES)    // 49152 int8 per tile (all channels)

typedef short bf16x8 __attribute__((ext_vector_type(8)));   // 8 bf16 (4 VGPRs)
typedef float floatx4 __attribute__((ext_vector_type(4)));
typedef unsigned int uintx2 __attribute__((ext_vector_type(2)));
typedef unsigned int uintx4 __attribute__((ext_vector_type(4)));

__device__ __forceinline__ unsigned pack_bf16_rne(float a, float b) {
    unsigned ua = __builtin_bit_cast(unsigned, a);
    unsigned ub = __builtin_bit_cast(unsigned, b);
    ua += 0x7FFFu + ((ua >> 16) & 1u);   // round-to-nearest-even
    ub += 0x7FFFu + ((ub >> 16) & 1u);
    return (ua >> 16) | (ub & 0xFFFF0000u);
}

// tanh via v_exp_f32: tanh|x| = 1 - 2/(exp(2|x|)+1); error ~1e-6 << 2e-2 threshold
__device__ __forceinline__ float fast_tanh(float x) {
    float ax = __builtin_fabsf(x);
    float e = __builtin_amdgcn_exp2f(ax * 2.8853900817779268f);  // 2*log2(e)
    float t = 1.0f - 2.0f * __builtin_amdgcn_rcpf(e + 1.0f);
    return __builtin_copysignf(t, x);
}

// Swizzled LDS byte offset for bf16 (row, d); row stride 256 B. XOR (row&7)<<4
// breaks the stride-256B column bank conflict (guide §6 G4), keeps 16B alignment.
__device__ __forceinline__ int lds_off(int row, int d) {
    return row * 256 + ((d * 2) ^ ((row & 7) << 4));
}

// Swizzled byte offset into the int8 transpose buffer [96][128]: row stride 128 B,
// XOR (n&7)<<4 -> 2 lanes/bank on ds_write_b32 (free, m136); 16B granules preserved.
__device__ __forceinline__ int t_off(int n, int e) {
    return n * 128 + (e ^ ((n & 7) << 4));
}

// W fragments in registers: bfr[et][s] = bf16 of W[e][s*32+(lane>>4)*8 .. +7],
// e = wave*32 + et*16 + (lane&15).
__device__ __forceinline__ void load_w_frags(const float* __restrict__ W,
                                             int wave, int lane, bf16x8 (&bfr)[2][4]) {
    int l15 = lane & 15, q = lane >> 4;
    #pragma unroll
    for (int et = 0; et < 2; ++et)
        #pragma unroll
        for (int s = 0; s < 4; ++s) {
            int e = wave * 32 + et * 16 + l15;
            int d0 = s * 32 + q * 8;
            const floatx4* p = reinterpret_cast<const floatx4*>(W + e * D_DIM + d0);
            floatx4 v0 = p[0], v1 = p[1];
            uintx4 u;
            u.x = pack_bf16_rne(v0.x, v0.y);
            u.y = pack_bf16_rne(v0.z, v0.w);
            u.z = pack_bf16_rne(v1.x, v1.y);
            u.w = pack_bf16_rne(v1.z, v1.w);
            bfr[et][s] = __builtin_bit_cast(bf16x8, u);
        }
}

// Pass 1: per (c, tile): z = hs_tile @ W^T (swapped operands -> lane holds 4 consecutive e);
// h = tanh(z+b); partial score = sum h.meta[c]; h -> int8, LDS-transpose, coalesced store.
__global__ __launch_bounds__(256, 6) void score_kernel(
        const float* __restrict__ hs, const float* __restrict__ W,
        const float* __restrict__ bvec, const float* __restrict__ meta,
        unsigned char* __restrict__ h8, float* __restrict__ partials) {
    __shared__ short As[M_TILE * D_DIM];     // 24 KB; reused as int8 transpose buffer
    __shared__ float red[4];
    int c = blockIdx.x, tile = blockIdx.y, tid = threadIdx.x;
    int wave = tid >> 6, lane = tid & 63;
    int l15 = lane & 15, q = lane >> 4;

    // issue ALL hs NT loads first (full vmcnt depth; hs read exactly once, keep out of L3)
    const float* src = hs + (size_t)c * N_NODES * D_DIM + (size_t)tile * M_TILE * D_DIM;
    floatx4 R[12];
    #pragma unroll
    for (int j = 0; j < 12; ++j)
        R[j] = __builtin_nontemporal_load(reinterpret_cast<const floatx4*>(src) + j * 256 + tid);

    bf16x8 bfr[2][4];
    load_w_frags(W, wave, lane, bfr);

    #pragma unroll
    for (int j = 0; j < 12; ++j) {              // pack + swizzled LDS write
        int qq = j * 256 + tid;
        int row = qq >> 5, d0 = (qq & 31) * 4;
        uintx2 w;
        w.x = pack_bf16_rne(R[j].x, R[j].y);
        w.y = pack_bf16_rne(R[j].z, R[j].w);
        *reinterpret_cast<uintx2*>(reinterpret_cast<char*>(As) + lds_off(row, d0)) = w;
    }
    __syncthreads();

    floatx4 acc[6][2];
    #pragma unroll
    for (int mt = 0; mt < 6; ++mt)
        #pragma unroll
        for (int et = 0; et < 2; ++et)
            acc[mt][et] = (floatx4){0.f, 0.f, 0.f, 0.f};

    #pragma unroll
    for (int s = 0; s < 4; ++s) {
        int d0 = s * 32 + q * 8;
        bf16x8 a[6];
        #pragma unroll
        for (int mt = 0; mt < 6; ++mt)
            a[mt] = *reinterpret_cast<const bf16x8*>(
                        reinterpret_cast<const char*>(As) + lds_off(mt * 16 + l15, d0));
        #pragma unroll
        for (int mt = 0; mt < 6; ++mt)
            #pragma unroll
            for (int et = 0; et < 2; ++et)
                acc[mt][et] = __builtin_amdgcn_mfma_f32_16x16x32_bf16(bfr[et][s], a[mt], acc[mt][et], 0, 0, 0);
    }

    // epilogue: lane holds z[n][e0..e0+3], n = mt*16+l15, e0 = wave*32+et*16+q*4
    floatx4 bvv[2], mvv[2];
    #pragma unroll
    for (int et = 0; et < 2; ++et) {
        int e0 = wave * 32 + et * 16 + q * 4;
        bvv[et] = *reinterpret_cast<const floatx4*>(bvec + e0);
        mvv[et] = *reinterpret_cast<const floatx4*>(meta + c * D_DIM + e0);
    }
    unsigned pk[6][2];
    float p = 0.f;
    #pragma unroll
    for (int mt = 0; mt < 6; ++mt)
        #pragma unroll
        for (int et = 0; et < 2; ++et) {
            unsigned u = 0;
            #pragma unroll
            for (int r = 0; r < 4; ++r) {
                float hv = fast_tanh(acc[mt][et][r] + bvv[et][r]);
                p += hv * mvv[et][r];
                int iq = (int)__builtin_rintf(hv * 127.0f);
                u |= ((unsigned)iq & 0xFFu) << (8 * r);
            }
            pk[mt][et] = u;
        }

    __syncthreads();   // all waves done reading As -> safe to reuse as transpose buffer
    char* tb = reinterpret_cast<char*>(As);
    #pragma unroll
    for (int mt = 0; mt < 6; ++mt)
        #pragma unroll
        for (int et = 0; et < 2; ++et) {
            int n = mt * 16 + l15;
            int e0 = wave * 32 + et * 16 + q * 4;
            *reinterpret_cast<unsigned*>(tb + t_off(n, e0)) = pk[mt][et];
        }
    __syncthreads();

    // coalesced writeback: each store INSTRUCTION is lane-contiguous (4 KB across the
    // block): chunk g16 = i*256 + tid owns bytes [g16*16, g16*16+16) of the [96][128] tile.
    unsigned char* dstc = h8 + (size_t)tile * H_TILE_BYTES + c * TILE_BYTES;
    #pragma unroll
    for (int i = 0; i < 3; ++i) {
        int g16 = i * 256 + tid;        // 16-byte chunk index (768 total)
        int n = g16 >> 3;               // 8 chunks per 128-B row
        int e = (g16 & 7) * 16;
        uintx4 v = *reinterpret_cast<const uintx4*>(tb + t_off(n, e));
        *reinterpret_cast<uintx4*>(dstc + g16 * 16) = v;
    }

    #pragma unroll
    for (int off = 32; off > 0; off >>= 1) p += __shfl_down(p, off);
    if (lane == 0) red[wave] = p;
    __syncthreads();
    if (tid == 0) partials[c * N_TILES + tile] = red[0] + red[1] + red[2] + red[3];
}

// Pass 2: every block redundantly reduces partials (fixed order -> deterministic,
// identical in all blocks; 50KB, L3-hot) and computes softmax locally, then
// out chunk g (16 B) = sum_c att[c]/127 * h8[c][...]. All load/store instructions
// lane-contiguous; reversed tile order for L3 hits on h8; NT out stores.
__global__ __launch_bounds__(256, 8) void combine_kernel(
        const unsigned char* __restrict__ h8, const float* __restrict__ partials,
        float* __restrict__ out) {
    __shared__ float red[4][C_CH];
    int tile = N_TILES - 1 - blockIdx.x;
    int tid = threadIdx.x, wave = tid >> 6, lane = tid & 63;

    float s[C_CH];
    #pragma unroll
    for (int c = 0; c < C_CH; ++c) s[c] = 0.f;
    for (int i = tid; i < N_TILES; i += 256) {
        #pragma unroll
        for (int c = 0; c < C_CH; ++c) s[c] += partials[c * N_TILES + i];
    }
    #pragma unroll
    for (int c = 0; c < C_CH; ++c) {
        float v = s[c];
        #pragma unroll
        for (int off = 32; off > 0; off >>= 1) v += __shfl_down(v, off);
        if (lane == 0) red[wave][c] = v;
    }
    __syncthreads();

    float av[C_CH], m = -1e30f, sum = 0.f;
    #pragma unroll
    for (int c = 0; c < C_CH; ++c) {
        av[c] = (red[0][c] + red[1][c] + red[2][c] + red[3][c]) / (float)N_NODES;
        m = fmaxf(m, av[c]);
    }
    #pragma unroll
    for (int c = 0; c < C_CH; ++c) {
        av[c] = __builtin_amdgcn_exp2f((av[c] - m) * 1.4426950408889634f);
        sum += av[c];
    }
    float inv = 1.0f / (sum * 127.0f);          // fold dequant scale
    #pragma unroll
    for (int c = 0; c < C_CH; ++c) av[c] *= inv;

    const unsigned char* base = h8 + (size_t)tile * H_TILE_BYTES;
    float* obase = out + (size_t)tile * (M_TILE * D_DIM);

    #pragma unroll
    for (int it = 0; it < 12; ++it) {           // 3072 float4-chunks / 256 threads
        int g = it * 256 + tid;                 // chunk index within tile
        float s0 = 0.f, s1 = 0.f, s2 = 0.f, s3 = 0.f;
        #pragma unroll
        for (int c = 0; c < C_CH; ++c) {
            unsigned u = *reinterpret_cast<const unsigned*>(base + c * TILE_BYTES + g * 4);
            s0 += av[c] * (float)((int)(u << 24) >> 24);
            s1 += av[c] * (float)((int)(u << 16) >> 24);
            s2 += av[c] * (float)((int)(u <<  8) >> 24);
            s3 += av[c] * (float)((int) u        >> 24);
        }
        floatx4 o = {s0, s1, s2, s3};
        __builtin_nontemporal_store(o, reinterpret_cast<floatx4*>(obase + g * 4));
    }
}

extern "C" void kernel_launch(void* const* d_in, const int* in_sizes, int n_in,
                              void* d_out, int out_size, void* d_ws, size_t ws_size,
                              hipStream_t stream) {
    (void)in_sizes; (void)n_in; (void)out_size; (void)ws_size;
    const float* hs   = (const float*)d_in[0];
    const float* W    = (const float*)d_in[1];
    const float* bv   = (const float*)d_in[2];
    const float* meta = (const float*)d_in[3];
    unsigned char* h8 = (unsigned char*)d_ws;                       // [3125][4][96][128] int8 = 153.6 MB
    float* partials = (float*)((char*)d_ws + 153600000);            // [4][3125]
    float* out      = (float*)d_out;

    // grid x = channel (fast), y = tile -> tile-major dispatch: last-written h8 tiles
    // (all 4 channels together) are the L3-resident tail for pass 2's reversed walk.
    score_kernel<<<dim3(C_CH, N_TILES), 256, 0, stream>>>(hs, W, bv, meta, h8, partials);
    combine_kernel<<<N_TILES, 256, 0, stream>>>(h8, partials, out);
}

// Round 11
// 214.323 us; speedup vs baseline: 1.9759x; 1.9759x over previous
//
#include <hip/hip_runtime.h>
#include <hip/hip_bf16.h>

// HeteroAttLayer: h = tanh(hs @ W^T + b); att = softmax(mean_n h.meta); out = sum_c att[c]*h[c]
// C=4, N=300000, D=128.
// R11 = R9 (score at launch_bounds (256,4) — R10's (256,6) forced VGPR=40 and spilled
//       ~690MB to scratch) + explicit issue-all-12-NT-loads staging batch (the half of
//       R10 the spill masked). Everything else identical to R9.

#define C_CH 4
#define N_NODES 300000
#define D_DIM 128
#define M_TILE 96
#define N_TILES (N_NODES / M_TILE)          // 3125 exactly, no tail
#define TILE_BYTES (M_TILE * D_DIM)         // 12288 int8 per (tile, channel)
#define H_TILE_BYTES (C_CH * TILE_BYTES)    // 49152 int8 per tile (all channels)

typedef short bf16x8 __attribute__((ext_vector_type(8)));   // 8 bf16 (4 VGPRs)
typedef float floatx4 __attribute__((ext_vector_type(4)));
typedef unsigned int uintx2 __attribute__((ext_vector_type(2)));
typedef unsigned int uintx4 __attribute__((ext_vector_type(4)));

__device__ __forceinline__ unsigned pack_bf16_rne(float a, float b) {
    unsigned ua = __builtin_bit_cast(unsigned, a);
    unsigned ub = __builtin_bit_cast(unsigned, b);
    ua += 0x7FFFu + ((ua >> 16) & 1u);   // round-to-nearest-even
    ub += 0x7FFFu + ((ub >> 16) & 1u);
    return (ua >> 16) | (ub & 0xFFFF0000u);
}

// tanh via v_exp_f32: tanh|x| = 1 - 2/(exp(2|x|)+1); error ~1e-6 << 2e-2 threshold
__device__ __forceinline__ float fast_tanh(float x) {
    float ax = __builtin_fabsf(x);
    float e = __builtin_amdgcn_exp2f(ax * 2.8853900817779268f);  // 2*log2(e)
    float t = 1.0f - 2.0f * __builtin_amdgcn_rcpf(e + 1.0f);
    return __builtin_copysignf(t, x);
}

// Swizzled LDS byte offset for bf16 (row, d); row stride 256 B. XOR (row&7)<<4
// breaks the stride-256B column bank conflict (guide §6 G4), keeps 16B alignment.
__device__ __forceinline__ int lds_off(int row, int d) {
    return row * 256 + ((d * 2) ^ ((row & 7) << 4));
}

// Swizzled byte offset into the int8 transpose buffer [96][128]: row stride 128 B,
// XOR (n&7)<<4 -> 2 lanes/bank on ds_write_b32 (free, m136); 16B granules preserved.
__device__ __forceinline__ int t_off(int n, int e) {
    return n * 128 + (e ^ ((n & 7) << 4));
}

// W fragments in registers: bfr[et][s] = bf16 of W[e][s*32+(lane>>4)*8 .. +7],
// e = wave*32 + et*16 + (lane&15).
__device__ __forceinline__ void load_w_frags(const float* __restrict__ W,
                                             int wave, int lane, bf16x8 (&bfr)[2][4]) {
    int l15 = lane & 15, q = lane >> 4;
    #pragma unroll
    for (int et = 0; et < 2; ++et)
        #pragma unroll
        for (int s = 0; s < 4; ++s) {
            int e = wave * 32 + et * 16 + l15;
            int d0 = s * 32 + q * 8;
            const floatx4* p = reinterpret_cast<const floatx4*>(W + e * D_DIM + d0);
            floatx4 v0 = p[0], v1 = p[1];
            uintx4 u;
            u.x = pack_bf16_rne(v0.x, v0.y);
            u.y = pack_bf16_rne(v0.z, v0.w);
            u.z = pack_bf16_rne(v1.x, v1.y);
            u.w = pack_bf16_rne(v1.z, v1.w);
            bfr[et][s] = __builtin_bit_cast(bf16x8, u);
        }
}

// Pass 1: per (c, tile): z = hs_tile @ W^T (swapped operands -> lane holds 4 consecutive e);
// h = tanh(z+b); partial score = sum h.meta[c]; h -> int8, LDS-transpose, coalesced store.
__global__ __launch_bounds__(256, 4) void score_kernel(
        const float* __restrict__ hs, const float* __restrict__ W,
        const float* __restrict__ bvec, const float* __restrict__ meta,
        unsigned char* __restrict__ h8, float* __restrict__ partials) {
    __shared__ short As[M_TILE * D_DIM];     // 24 KB; reused as int8 transpose buffer
    __shared__ float red[4];
    int c = blockIdx.x, tile = blockIdx.y, tid = threadIdx.x;
    int wave = tid >> 6, lane = tid & 63;
    int l15 = lane & 15, q = lane >> 4;

    // issue ALL hs NT loads first (12-deep vmcnt batch; hs read exactly once -> NT keeps
    // it out of L3 so the resident h8 working set survives)
    const float* src = hs + (size_t)c * N_NODES * D_DIM + (size_t)tile * M_TILE * D_DIM;
    floatx4 R[12];
    #pragma unroll
    for (int j = 0; j < 12; ++j)
        R[j] = __builtin_nontemporal_load(reinterpret_cast<const floatx4*>(src) + j * 256 + tid);

    bf16x8 bfr[2][4];
    load_w_frags(W, wave, lane, bfr);

    #pragma unroll
    for (int j = 0; j < 12; ++j) {              // pack + swizzled LDS write
        int qq = j * 256 + tid;
        int row = qq >> 5, d0 = (qq & 31) * 4;
        uintx2 w;
        w.x = pack_bf16_rne(R[j].x, R[j].y);
        w.y = pack_bf16_rne(R[j].z, R[j].w);
        *reinterpret_cast<uintx2*>(reinterpret_cast<char*>(As) + lds_off(row, d0)) = w;
    }
    __syncthreads();

    floatx4 acc[6][2];
    #pragma unroll
    for (int mt = 0; mt < 6; ++mt)
        #pragma unroll
        for (int et = 0; et < 2; ++et)
            acc[mt][et] = (floatx4){0.f, 0.f, 0.f, 0.f};

    #pragma unroll
    for (int s = 0; s < 4; ++s) {
        int d0 = s * 32 + q * 8;
        bf16x8 a[6];
        #pragma unroll
        for (int mt = 0; mt < 6; ++mt)
            a[mt] = *reinterpret_cast<const bf16x8*>(
                        reinterpret_cast<const char*>(As) + lds_off(mt * 16 + l15, d0));
        #pragma unroll
        for (int mt = 0; mt < 6; ++mt)
            #pragma unroll
            for (int et = 0; et < 2; ++et)
                acc[mt][et] = __builtin_amdgcn_mfma_f32_16x16x32_bf16(bfr[et][s], a[mt], acc[mt][et], 0, 0, 0);
    }

    // epilogue: lane holds z[n][e0..e0+3], n = mt*16+l15, e0 = wave*32+et*16+q*4
    floatx4 bvv[2], mvv[2];
    #pragma unroll
    for (int et = 0; et < 2; ++et) {
        int e0 = wave * 32 + et * 16 + q * 4;
        bvv[et] = *reinterpret_cast<const floatx4*>(bvec + e0);
        mvv[et] = *reinterpret_cast<const floatx4*>(meta + c * D_DIM + e0);
    }
    unsigned pk[6][2];
    float p = 0.f;
    #pragma unroll
    for (int mt = 0; mt < 6; ++mt)
        #pragma unroll
        for (int et = 0; et < 2; ++et) {
            unsigned u = 0;
            #pragma unroll
            for (int r = 0; r < 4; ++r) {
                float hv = fast_tanh(acc[mt][et][r] + bvv[et][r]);
                p += hv * mvv[et][r];
                int iq = (int)__builtin_rintf(hv * 127.0f);
                u |= ((unsigned)iq & 0xFFu) << (8 * r);
            }
            pk[mt][et] = u;
        }

    __syncthreads();   // all waves done reading As -> safe to reuse as transpose buffer
    char* tb = reinterpret_cast<char*>(As);
    #pragma unroll
    for (int mt = 0; mt < 6; ++mt)
        #pragma unroll
        for (int et = 0; et < 2; ++et) {
            int n = mt * 16 + l15;
            int e0 = wave * 32 + et * 16 + q * 4;
            *reinterpret_cast<unsigned*>(tb + t_off(n, e0)) = pk[mt][et];
        }
    __syncthreads();

    // coalesced writeback: each store INSTRUCTION is lane-contiguous (4 KB across the
    // block): chunk g16 = i*256 + tid owns bytes [g16*16, g16*16+16) of the [96][128] tile.
    unsigned char* dstc = h8 + (size_t)tile * H_TILE_BYTES + c * TILE_BYTES;
    #pragma unroll
    for (int i = 0; i < 3; ++i) {
        int g16 = i * 256 + tid;        // 16-byte chunk index (768 total)
        int n = g16 >> 3;               // 8 chunks per 128-B row
        int e = (g16 & 7) * 16;
        uintx4 v = *reinterpret_cast<const uintx4*>(tb + t_off(n, e));
        *reinterpret_cast<uintx4*>(dstc + g16 * 16) = v;
    }

    #pragma unroll
    for (int off = 32; off > 0; off >>= 1) p += __shfl_down(p, off);
    if (lane == 0) red[wave] = p;
    __syncthreads();
    if (tid == 0) partials[c * N_TILES + tile] = red[0] + red[1] + red[2] + red[3];
}

// Pass 2: every block redundantly reduces partials (fixed order -> deterministic,
// identical in all blocks; 50KB, L3-hot) and computes softmax locally, then
// out chunk g (16 B) = sum_c att[c]/127 * h8[c][...]. All load/store instructions
// lane-contiguous; reversed tile order for L3 hits on h8; NT out stores.
__global__ __launch_bounds__(256, 8) void combine_kernel(
        const unsigned char* __restrict__ h8, const float* __restrict__ partials,
        float* __restrict__ out) {
    __shared__ float red[4][C_CH];
    int tile = N_TILES - 1 - blockIdx.x;
    int tid = threadIdx.x, wave = tid >> 6, lane = tid & 63;

    float s[C_CH];
    #pragma unroll
    for (int c = 0; c < C_CH; ++c) s[c] = 0.f;
    for (int i = tid; i < N_TILES; i += 256) {
        #pragma unroll
        for (int c = 0; c < C_CH; ++c) s[c] += partials[c * N_TILES + i];
    }
    #pragma unroll
    for (int c = 0; c < C_CH; ++c) {
        float v = s[c];
        #pragma unroll
        for (int off = 32; off > 0; off >>= 1) v += __shfl_down(v, off);
        if (lane == 0) red[wave][c] = v;
    }
    __syncthreads();

    float av[C_CH], m = -1e30f, sum = 0.f;
    #pragma unroll
    for (int c = 0; c < C_CH; ++c) {
        av[c] = (red[0][c] + red[1][c] + red[2][c] + red[3][c]) / (float)N_NODES;
        m = fmaxf(m, av[c]);
    }
    #pragma unroll
    for (int c = 0; c < C_CH; ++c) {
        av[c] = __builtin_amdgcn_exp2f((av[c] - m) * 1.4426950408889634f);
        sum += av[c];
    }
    float inv = 1.0f / (sum * 127.0f);          // fold dequant scale
    #pragma unroll
    for (int c = 0; c < C_CH; ++c) av[c] *= inv;

    const unsigned char* base = h8 + (size_t)tile * H_TILE_BYTES;
    float* obase = out + (size_t)tile * (M_TILE * D_DIM);

    #pragma unroll
    for (int it = 0; it < 12; ++it) {           // 3072 float4-chunks / 256 threads
        int g = it * 256 + tid;                 // chunk index within tile
        float s0 = 0.f, s1 = 0.f, s2 = 0.f, s3 = 0.f;
        #pragma unroll
        for (int c = 0; c < C_CH; ++c) {
            unsigned u = *reinterpret_cast<const unsigned*>(base + c * TILE_BYTES + g * 4);
            s0 += av[c] * (float)((int)(u << 24) >> 24);
            s1 += av[c] * (float)((int)(u << 16) >> 24);
            s2 += av[c] * (float)((int)(u <<  8) >> 24);
            s3 += av[c] * (float)((int) u        >> 24);
        }
        floatx4 o = {s0, s1, s2, s3};
        __builtin_nontemporal_store(o, reinterpret_cast<floatx4*>(obase + g * 4));
    }
}

extern "C" void kernel_launch(void* const* d_in, const int* in_sizes, int n_in,
                              void* d_out, int out_size, void* d_ws, size_t ws_size,
                              hipStream_t stream) {
    (void)in_sizes; (void)n_in; (void)out_size; (void)ws_size;
    const float* hs   = (const float*)d_in[0];
    const float* W    = (const float*)d_in[1];
    const float* bv   = (const float*)d_in[2];
    const float* meta = (const float*)d_in[3];
    unsigned char* h8 = (unsigned char*)d_ws;                       // [3125][4][96][128] int8 = 153.6 MB
    float* partials = (float*)((char*)d_ws + 153600000);            // [4][3125]
    float* out      = (float*)d_out;

    // grid x = channel (fast), y = tile -> tile-major dispatch: last-written h8 tiles
    // (all 4 channels together) are the L3-resident tail for pass 2's reversed walk.
    score_kernel<<<dim3(C_CH, N_TILES), 256, 0, stream>>>(hs, W, bv, meta, h8, partials);
    combine_kernel<<<N_TILES, 256, 0, stream>>>(h8, partials, out);
}